// Round 5
// baseline (884.777 us; speedup 1.0000x reference)
//
#include <hip/hip_runtime.h>
#include <hip/hip_fp16.h>

constexpr int D_IN = 256, D_HID = 512, D_OUT = 48;
constexpr int K_STEPS = 10;

typedef __attribute__((ext_vector_type(8))) __bf16 bf16x8;
typedef __attribute__((ext_vector_type(4))) float f32x4;

__device__ __forceinline__ unsigned short f2bf(float f) {
  unsigned u = __builtin_bit_cast(unsigned, f);
  u += 0x7fffu + ((u >> 16) & 1u);   // round-to-nearest-even
  return (unsigned short)(u >> 16);
}

// ---------------- graph build ----------------

__global__ void zero2_kernel(int* __restrict__ a, int* __restrict__ b, int N) {
  int i = blockIdx.x * 256 + threadIdx.x;
  if (i < N) { a[i] = 0; b[i] = 0; }
}

__global__ void count_kernel(const int* __restrict__ dst, int* __restrict__ cnt, int E) {
  int e = blockIdx.x * 256 + threadIdx.x;
  if (e < E) atomicAdd(&cnt[dst[e]], 1);
}

__global__ void dinv_kernel(const int* __restrict__ cnt, float* __restrict__ dinv, int N) {
  int n = blockIdx.x * 256 + threadIdx.x;
  if (n < N) dinv[n] = rsqrtf((float)(cnt[n] + 1));  // +1 = self-loop
}

// exclusive scan of PADDED cnt -> row_ptr (degree padded to multiple of 4)
__global__ void scan1_kernel(const int* __restrict__ cnt, int* __restrict__ row_ptr,
                             int* __restrict__ bsum, int N) {
  __shared__ int sd[256];
  int tid = threadIdx.x, b = blockIdx.x;
  int i0 = b * 1024 + tid * 4;
  int v[4];
#pragma unroll
  for (int m = 0; m < 4; ++m) v[m] = (i0 + m < N) ? ((cnt[i0 + m] + 3) & ~3) : 0;
  int s = v[0] + v[1] + v[2] + v[3];
  sd[tid] = s;
  __syncthreads();
  for (int off = 1; off < 256; off <<= 1) {
    int t = (tid >= off) ? sd[tid - off] : 0;
    __syncthreads();
    sd[tid] += t;
    __syncthreads();
  }
  int run = sd[tid] - s;
#pragma unroll
  for (int m = 0; m < 4; ++m) {
    if (i0 + m < N) row_ptr[i0 + m] = run;
    run += v[m];
  }
  if (tid == 255) bsum[b] = sd[255];
}

__global__ void scan2_kernel(const int* __restrict__ bsum, int* __restrict__ bofs,
                             int* __restrict__ row_ptr, int NB, int N) {
  __shared__ int sd[128];
  int tid = threadIdx.x;
  int v = (tid < NB) ? bsum[tid] : 0;
  sd[tid] = v;
  __syncthreads();
  for (int off = 1; off < 128; off <<= 1) {
    int t = (tid >= off) ? sd[tid - off] : 0;
    __syncthreads();
    sd[tid] += t;
    __syncthreads();
  }
  if (tid < NB) bofs[tid] = sd[tid] - v;
  if (tid == 127) row_ptr[N] = sd[127];
}

__global__ void scan3_kernel(int* __restrict__ row_ptr, const int* __restrict__ bofs, int N) {
  int b = blockIdx.x;
  if (b == 0) return;
  int add = bofs[b];
  int i0 = b * 1024 + threadIdx.x * 4;
#pragma unroll
  for (int m = 0; m < 4; ++m)
    if (i0 + m < N) row_ptr[i0 + m] += add;
}

// edges[p] = {src, dinv[src] bits}
__global__ void fill_kernel(const int* __restrict__ src, const int* __restrict__ dst,
                            const int* __restrict__ row_ptr, int* __restrict__ cnt2,
                            const float* __restrict__ dinv,
                            int2* __restrict__ edges, int E) {
  int e = blockIdx.x * 256 + threadIdx.x;
  if (e >= E) return;
  int s = src[e], d = dst[e];
  int p = row_ptr[d] + atomicAdd(&cnt2[d], 1);
  edges[p] = make_int2(s, __float_as_int(dinv[s]));
}

// fill padded tail records with zero-weight self edges
__global__ void pad_kernel(const int* __restrict__ cnt, const int* __restrict__ row_ptr,
                           int2* __restrict__ edges, int N) {
  int n = blockIdx.x * 256 + threadIdx.x;
  if (n >= N) return;
  int a = row_ptr[n] + cnt[n];
  int b = row_ptr[n + 1];
  for (int p = a; p < b; ++p) edges[p] = make_int2(n, 0);
}

// ---------------- conversions ----------------

__global__ void xcast_kernel(const float* __restrict__ x,
                             unsigned short* __restrict__ xb, int total8) {
  int i = blockIdx.x * 256 + threadIdx.x;
  if (i >= total8) return;
  const float4* p = (const float4*)(x + (size_t)i * 8);
  float4 a = p[0], b = p[1];
  unsigned short o[8] = {f2bf(a.x), f2bf(a.y), f2bf(a.z), f2bf(a.w),
                         f2bf(b.x), f2bf(b.y), f2bf(b.z), f2bf(b.w)};
  *(uint4*)(xb + (size_t)i * 8) = *(const uint4*)o;
}

__global__ void convert_w1(const float* __restrict__ W1, unsigned short* __restrict__ W1T) {
  int i = blockIdx.x * 256 + threadIdx.x;  // W1T[c][k], c<512, k<256
  if (i >= D_HID * D_IN) return;
  int c = i >> 8, k = i & 255;
  W1T[i] = f2bf(W1[k * D_HID + c]);
}

__global__ void convert_w2(const float* __restrict__ W2, unsigned short* __restrict__ W2T) {
  int i = blockIdx.x * 256 + threadIdx.x;  // W2T[n][k], n<48, k<512
  if (i >= D_OUT * D_HID) return;
  int n = i >> 9, k = i & 511;
  W2T[i] = f2bf(W2[k * D_OUT + n]);
}

// ---------------- fused MLP encoder (bf16 x, register-prefetched staging) ----------------
// 128 rows / block, 4 waves, A-frags (bf16) direct from global into VGPRs.
// 16 stages (ct 0..7 x kh 0..1): stage s+1's W1T/W2 tiles are loaded into
// registers during stage s's MFMA phase; barriers only wait on ds_writes.

__global__ __launch_bounds__(256, 3) void encoder_kernel(
    const unsigned short* __restrict__ xb,    // [N][256] bf16
    const float* __restrict__ b1, const float* __restrict__ b2,
    const unsigned short* __restrict__ W1T,   // [512][256] bf16
    const unsigned short* __restrict__ W2T,   // [48][512]  bf16
    __half* __restrict__ h2, int N) {
  __shared__ unsigned short sB[64][136];    // W1T tile: c(64) x k(128), pad 8
  __shared__ unsigned short sHid[128][72];  // m x hid-col(64), wave-private rows
  __shared__ unsigned short sW2[48][72];    // n(48) x hid-col(64)

  int tid = threadIdx.x;
  int w = tid >> 6, lane = tid & 63;
  int q = lane >> 4, l15 = lane & 15;
  int row0 = blockIdx.x * 128;
  int m0 = w * 16;
  int sr = tid >> 4, sc = tid & 15;          // sB staging row/col
  int w2r0 = tid >> 3, w2c0 = tid & 7;       // sW2 staging
  int w2id1 = 256 + tid;

  // A fragments: 2 tiles x 16 rows x K=256, direct bf16 loads (64 VGPRs)
  uint4 axu[2][8];
#pragma unroll
  for (int mt = 0; mt < 2; ++mt) {
    int grow = row0 + mt * 64 + m0 + l15;
    bool rok = grow < N;
    const unsigned short* xr = xb + (size_t)grow * D_IN;
#pragma unroll
    for (int jb = 0; jb < 8; ++jb)
      axu[mt][jb] = rok ? *(const uint4*)(xr + jb * 32 + q * 8)
                        : make_uint4(0, 0, 0, 0);
  }

  // preload stage 0 (ct=0, kh=0) into regs
  uint4 pre[4], w2p[2];
#pragma unroll
  for (int i = 0; i < 4; ++i)
    pre[i] = *(const uint4*)(W1T + (size_t)(sr + i * 16) * D_IN + sc * 8);
  w2p[0] = *(const uint4*)(W2T + (size_t)w2r0 * D_HID + w2c0 * 8);
  if (w2id1 < 384)
    w2p[1] = *(const uint4*)(W2T + (size_t)(w2id1 >> 3) * D_HID + (w2id1 & 7) * 8);

  f32x4 hacc[2][3];
#pragma unroll
  for (int mt = 0; mt < 2; ++mt)
#pragma unroll
    for (int t = 0; t < 3; ++t)
#pragma unroll
      for (int r = 0; r < 4; ++r) hacc[mt][t][r] = 0.f;

  f32x4 acc[2][4];
  for (int st = 0; st < 16; ++st) {
    int ct = st >> 1, kh = st & 1;
    int c0 = ct * 64;
    __syncthreads();   // bar A: all waves done reading sB (and sW2 if kh==0)
#pragma unroll
    for (int i = 0; i < 4; ++i)
      *(uint4*)&sB[sr + i * 16][sc * 8] = pre[i];
    if (kh == 0) {
      *(uint4*)&sW2[w2r0][w2c0 * 8] = w2p[0];
      if (w2id1 < 384) *(uint4*)&sW2[w2id1 >> 3][(w2id1 & 7) * 8] = w2p[1];
    }
    __syncthreads();   // bar B
    // prefetch stage st+1 into regs (overlaps MFMA below)
    if (st < 15) {
      int ct2 = (st + 1) >> 1, kh2 = (st + 1) & 1;
      const unsigned short* wb = W1T + (size_t)(ct2 * 64) * D_IN + kh2 * 128;
#pragma unroll
      for (int i = 0; i < 4; ++i)
        pre[i] = *(const uint4*)(wb + (size_t)(sr + i * 16) * D_IN + sc * 8);
      if (kh2 == 0) {
        int c02 = ct2 * 64;
        w2p[0] = *(const uint4*)(W2T + (size_t)w2r0 * D_HID + c02 + w2c0 * 8);
        if (w2id1 < 384)
          w2p[1] = *(const uint4*)(W2T + (size_t)(w2id1 >> 3) * D_HID + c02 + (w2id1 & 7) * 8);
      }
    }
    if (kh == 0) {
#pragma unroll
      for (int mt = 0; mt < 2; ++mt)
#pragma unroll
        for (int t = 0; t < 4; ++t)
#pragma unroll
          for (int r = 0; r < 4; ++r) acc[mt][t][r] = 0.f;
    }
#pragma unroll
    for (int kb = 0; kb < 4; ++kb) {
      bf16x8 a0 = __builtin_bit_cast(bf16x8, axu[0][kh * 4 + kb]);
      bf16x8 a1 = __builtin_bit_cast(bf16x8, axu[1][kh * 4 + kb]);
#pragma unroll
      for (int tn = 0; tn < 4; ++tn) {
        bf16x8 b = *(const bf16x8*)&sB[tn * 16 + l15][kb * 32 + q * 8];
        acc[0][tn] = __builtin_amdgcn_mfma_f32_16x16x32_bf16(a0, b, acc[0][tn], 0, 0, 0);
        acc[1][tn] = __builtin_amdgcn_mfma_f32_16x16x32_bf16(a1, b, acc[1][tn], 0, 0, 0);
      }
    }
    if (kh == 1) {
      // relu(acc + b1) -> sHid (wave-private rows), then GEMM2 on this ct chunk
#pragma unroll
      for (int mt = 0; mt < 2; ++mt)
#pragma unroll
        for (int tn = 0; tn < 4; ++tn) {
          int c = tn * 16 + l15;
          float bias = b1[c0 + c];
#pragma unroll
          for (int rg = 0; rg < 4; ++rg) {
            float v = acc[mt][tn][rg] + bias;
            v = v > 0.f ? v : 0.f;
            sHid[mt * 64 + m0 + q * 4 + rg][c] = f2bf(v);
          }
        }
#pragma unroll
      for (int kk = 0; kk < 2; ++kk) {
        bf16x8 a0 = *(const bf16x8*)&sHid[m0 + l15][kk * 32 + q * 8];
        bf16x8 a1 = *(const bf16x8*)&sHid[64 + m0 + l15][kk * 32 + q * 8];
#pragma unroll
        for (int tn = 0; tn < 3; ++tn) {
          bf16x8 b = *(const bf16x8*)&sW2[tn * 16 + l15][kk * 32 + q * 8];
          hacc[0][tn] = __builtin_amdgcn_mfma_f32_16x16x32_bf16(a0, b, hacc[0][tn], 0, 0, 0);
          hacc[1][tn] = __builtin_amdgcn_mfma_f32_16x16x32_bf16(a1, b, hacc[1][tn], 0, 0, 0);
        }
      }
    }
  }
  // epilogue: h2 = f16(hacc + b2), stride 48 (no padding)
#pragma unroll
  for (int mt = 0; mt < 2; ++mt)
#pragma unroll
    for (int tn = 0; tn < 3; ++tn) {
      int c = tn * 16 + l15;
      float bias = b2[c];
#pragma unroll
      for (int rg = 0; rg < 4; ++rg) {
        int gr = row0 + mt * 64 + m0 + q * 4 + rg;
        if (gr < N) h2[(size_t)gr * D_OUT + c] = __float2half(hacc[mt][tn][rg] + bias);
      }
    }
}

// ---------------- APPNP propagation ----------------
// 96-B rows (48 f16, no pad). wave = 2 nodes x 4 edge-slots x 8 chunks of 12 B.
// Unrolled 2 batches: 2 records + 2 independent gathers in flight per wave.

__device__ __forceinline__ void fma6(float* acc, float wgt, uint3 g) {
  float2 f0 = __half22float2(__builtin_bit_cast(__half2, g.x));
  float2 f1 = __half22float2(__builtin_bit_cast(__half2, g.y));
  float2 f2 = __half22float2(__builtin_bit_cast(__half2, g.z));
  acc[0] += wgt * f0.x; acc[1] += wgt * f0.y;
  acc[2] += wgt * f1.x; acc[3] += wgt * f1.y;
  acc[4] += wgt * f2.x; acc[5] += wgt * f2.y;
}

__global__ __launch_bounds__(256) void prop_kernel(
    const __half* __restrict__ cur, const __half* __restrict__ h2,
    const float* __restrict__ dinv, const int* __restrict__ row_ptr,
    const int2* __restrict__ edges, __half* __restrict__ nxt,
    float* __restrict__ outf, int N, int last) {
  int wid = (blockIdx.x * 256 + threadIdx.x) >> 6;
  int lane = threadIdx.x & 63;
  int half = lane >> 5;
  int slot = (lane >> 3) & 3;
  int s = lane & 7;
  int node = wid * 2 + half;
  bool nok = node < N;
  int p0 = 0, p1 = 0;
  if (nok) { int2 pp = *(const int2*)(row_ptr + node); p0 = pp.x; p1 = pp.y; }
  int d = p1 - p0;                          // padded degree (mult of 4)
  int dmax = max(d, __shfl_xor(d, 32));     // pair max (wave-uniform)
  int nb = dmax >> 2;

  float acc[6];
#pragma unroll
  for (int i = 0; i < 6; ++i) acc[i] = 0.f;

  int p = p0 + slot;
  int2 e0 = make_int2(0, 0), e1 = make_int2(0, 0);
  if (nb > 0) e0 = edges[p];
  if (nb > 1) e1 = edges[p + 4];
  int b = 0;
  for (; b + 2 <= nb; b += 2) {
    int2 n0 = make_int2(0, 0), n1 = make_int2(0, 0);
    if (b + 2 < nb) n0 = edges[p + 8];      // prefetch (uniform branches)
    if (b + 3 < nb) n1 = edges[p + 12];
    float w0 = (p < p1) ? __int_as_float(e0.y) : 0.f;
    float w1 = (p + 4 < p1) ? __int_as_float(e1.y) : 0.f;
    uint3 g0 = *(const uint3*)(cur + (size_t)e0.x * 48 + s * 6);
    uint3 g1 = *(const uint3*)(cur + (size_t)e1.x * 48 + s * 6);
    fma6(acc, w0, g0);
    fma6(acc, w1, g1);
    e0 = n0; e1 = n1; p += 8;
  }
  if (b < nb) {
    float w0 = (p < p1) ? __int_as_float(e0.y) : 0.f;
    uint3 g0 = *(const uint3*)(cur + (size_t)e0.x * 48 + s * 6);
    fma6(acc, w0, g0);
  }
  // fold the 4 slots (lane bits 3,4) via fixed-pattern swizzles
#pragma unroll
  for (int i = 0; i < 6; ++i) {
    acc[i] += __int_as_float(__builtin_amdgcn_ds_swizzle(__float_as_int(acc[i]), 0x201F)); // ^8
    acc[i] += __int_as_float(__builtin_amdgcn_ds_swizzle(__float_as_int(acc[i]), 0x401F)); // ^16
  }
  if ((lane & 24) != 0 || !nok) return;
  float di = dinv[node];
  size_t base = (size_t)node * 48 + s * 6;
  uint3 su = *(const uint3*)(cur + base);
  uint3 hu = *(const uint3*)(h2 + base);
  float dii = di * di;
  float sf[6], hf[6];
  {
    float2 t;
    t = __half22float2(__builtin_bit_cast(__half2, su.x)); sf[0] = t.x; sf[1] = t.y;
    t = __half22float2(__builtin_bit_cast(__half2, su.y)); sf[2] = t.x; sf[3] = t.y;
    t = __half22float2(__builtin_bit_cast(__half2, su.z)); sf[4] = t.x; sf[5] = t.y;
    t = __half22float2(__builtin_bit_cast(__half2, hu.x)); hf[0] = t.x; hf[1] = t.y;
    t = __half22float2(__builtin_bit_cast(__half2, hu.y)); hf[2] = t.x; hf[3] = t.y;
    t = __half22float2(__builtin_bit_cast(__half2, hu.z)); hf[4] = t.x; hf[5] = t.y;
  }
  float outv[6];
#pragma unroll
  for (int i = 0; i < 6; ++i)
    outv[i] = 0.9f * (di * acc[i] + dii * sf[i]) + 0.1f * hf[i];
  if (last) {
    float* op = outf + base;
    *(float2*)op       = make_float2(outv[0], outv[1]);
    *(float2*)(op + 2) = make_float2(outv[2], outv[3]);
    *(float2*)(op + 4) = make_float2(outv[4], outv[5]);
  } else {
    uint3 o;
    o.x = __builtin_bit_cast(unsigned, __floats2half2_rn(outv[0], outv[1]));
    o.y = __builtin_bit_cast(unsigned, __floats2half2_rn(outv[2], outv[3]));
    o.z = __builtin_bit_cast(unsigned, __floats2half2_rn(outv[4], outv[5]));
    *(uint3*)(nxt + base) = o;
  }
}

// ---------------- launch ----------------

extern "C" void kernel_launch(void* const* d_in, const int* in_sizes, int n_in,
                              void* d_out, int out_size, void* d_ws, size_t ws_size,
                              hipStream_t stream) {
  (void)n_in; (void)out_size; (void)ws_size;
  const float* x  = (const float*)d_in[0];
  const int*   ei = (const int*)d_in[1];
  const float* W1 = (const float*)d_in[2];
  const float* b1 = (const float*)d_in[3];
  const float* W2 = (const float*)d_in[4];
  const float* b2 = (const float*)d_in[5];
  const int N = in_sizes[0] / D_IN;
  const int E = in_sizes[1] / 2;
  const int* e_src = ei;
  const int* e_dst = ei + E;

  char* ws = (char*)d_ws;
  size_t off = 0;
  auto take = [&](size_t bytes) -> char* {
    char* p = ws + off;
    off += (bytes + 511) & ~(size_t)511;
    return p;
  };
  int* cnt      = (int*)take((size_t)N * 4);
  int* cnt2     = (int*)take((size_t)N * 4);
  float* dinv   = (float*)take((size_t)N * 4);
  int* row_ptr  = (int*)take((size_t)(N + 1) * 4);
  int* bsum     = (int*)take(1024);
  int* bofs     = (int*)take(1024);
  int2* edges   = (int2*)take(((size_t)E + 4 * (size_t)N) * 8);  // padded CSR
  unsigned short* xb  = (unsigned short*)take((size_t)N * D_IN * 2);
  unsigned short* W1T = (unsigned short*)take((size_t)D_IN * D_HID * 2);
  unsigned short* W2T = (unsigned short*)take((size_t)D_HID * D_OUT * 2);
  __half* h2    = (__half*)take((size_t)N * D_OUT * 2);
  __half* bufA  = (__half*)take((size_t)N * D_OUT * 2);
  __half* bufB  = (__half*)d_out;   // 19.2 MB f32 out region holds the 9.6 MB f16 buf;
                                    // last read of bufB is before final f32 write
  float* outp   = (float*)d_out;

  int nb256 = (N + 255) / 256;
  int eb256 = (E + 255) / 256;
  int NB    = (N + 1023) / 1024;   // 98 <= 128 ok

  // graph build (padded CSR)
  zero2_kernel<<<nb256, 256, 0, stream>>>(cnt, cnt2, N);
  count_kernel<<<eb256, 256, 0, stream>>>(e_dst, cnt, E);
  dinv_kernel<<<nb256, 256, 0, stream>>>(cnt, dinv, N);
  scan1_kernel<<<NB, 256, 0, stream>>>(cnt, row_ptr, bsum, N);
  scan2_kernel<<<1, 128, 0, stream>>>(bsum, bofs, row_ptr, NB, N);
  scan3_kernel<<<NB, 256, 0, stream>>>(row_ptr, bofs, N);
  fill_kernel<<<eb256, 256, 0, stream>>>(e_src, e_dst, row_ptr, cnt2, dinv, edges, E);
  pad_kernel<<<nb256, 256, 0, stream>>>(cnt, row_ptr, edges, N);

  // conversions + encoder
  int total8 = N * D_IN / 8;
  xcast_kernel<<<(total8 + 255) / 256, 256, 0, stream>>>(x, xb, total8);
  convert_w1<<<(D_IN * D_HID + 255) / 256, 256, 0, stream>>>(W1, W1T);
  convert_w2<<<(D_HID * D_OUT + 255) / 256, 256, 0, stream>>>(W2, W2T);
  encoder_kernel<<<(N + 127) / 128, 256, 0, stream>>>(xb, b1, b2, W1T, W2T, h2, N);

  // APPNP: 10 iters; h2 -> A -> B(d_out) -> A ... ; last writes f32 d_out
  int waves = (N + 1) / 2;
  int pblocks = (waves + 3) / 4;
  const __half* src = h2;
  __half* dst = bufA;
  for (int it = 1; it <= K_STEPS; ++it) {
    int last = (it == K_STEPS);
    prop_kernel<<<pblocks, 256, 0, stream>>>(src, h2, dinv, row_ptr, edges,
                                             dst, outp, N, last);
    src = dst;
    dst = (dst == bufA) ? bufB : bufA;
  }
}

// Round 6
// 742.978 us; speedup vs baseline: 1.1909x; 1.1909x over previous
//
#include <hip/hip_runtime.h>
#include <hip/hip_fp16.h>

constexpr int D_IN = 256, D_HID = 512, D_OUT = 48;
constexpr int HPAD = 64;   // padded feature stride (f16) -> 128 B rows for prop
constexpr int K_STEPS = 10;

typedef __attribute__((ext_vector_type(8))) __bf16 bf16x8;
typedef __attribute__((ext_vector_type(4))) float f32x4;

__device__ __forceinline__ unsigned short f2bf(float f) {
  unsigned u = __builtin_bit_cast(unsigned, f);
  u += 0x7fffu + ((u >> 16) & 1u);   // round-to-nearest-even
  return (unsigned short)(u >> 16);
}

// ---------------- graph build ----------------

__global__ void zero2_kernel(int* __restrict__ a, int* __restrict__ b, int N) {
  int i = blockIdx.x * 256 + threadIdx.x;
  if (i < N) { a[i] = 0; b[i] = 0; }
}

__global__ void count_kernel(const int* __restrict__ dst, int* __restrict__ cnt, int E) {
  int e = blockIdx.x * 256 + threadIdx.x;
  if (e < E) atomicAdd(&cnt[dst[e]], 1);
}

__global__ void dinv_kernel(const int* __restrict__ cnt, float* __restrict__ dinv, int N) {
  int n = blockIdx.x * 256 + threadIdx.x;
  if (n < N) dinv[n] = rsqrtf((float)(cnt[n] + 1));  // +1 = self-loop
}

// exclusive scan of PADDED cnt -> row_ptr (degree padded to multiple of 4)
__global__ void scan1_kernel(const int* __restrict__ cnt, int* __restrict__ row_ptr,
                             int* __restrict__ bsum, int N) {
  __shared__ int sd[256];
  int tid = threadIdx.x, b = blockIdx.x;
  int i0 = b * 1024 + tid * 4;
  int v[4];
#pragma unroll
  for (int m = 0; m < 4; ++m) v[m] = (i0 + m < N) ? ((cnt[i0 + m] + 3) & ~3) : 0;
  int s = v[0] + v[1] + v[2] + v[3];
  sd[tid] = s;
  __syncthreads();
  for (int off = 1; off < 256; off <<= 1) {
    int t = (tid >= off) ? sd[tid - off] : 0;
    __syncthreads();
    sd[tid] += t;
    __syncthreads();
  }
  int run = sd[tid] - s;
#pragma unroll
  for (int m = 0; m < 4; ++m) {
    if (i0 + m < N) row_ptr[i0 + m] = run;
    run += v[m];
  }
  if (tid == 255) bsum[b] = sd[255];
}

__global__ void scan2_kernel(const int* __restrict__ bsum, int* __restrict__ bofs,
                             int* __restrict__ row_ptr, int NB, int N) {
  __shared__ int sd[128];
  int tid = threadIdx.x;
  int v = (tid < NB) ? bsum[tid] : 0;
  sd[tid] = v;
  __syncthreads();
  for (int off = 1; off < 128; off <<= 1) {
    int t = (tid >= off) ? sd[tid - off] : 0;
    __syncthreads();
    sd[tid] += t;
    __syncthreads();
  }
  if (tid < NB) bofs[tid] = sd[tid] - v;
  if (tid == 127) row_ptr[N] = sd[127];
}

__global__ void scan3_kernel(int* __restrict__ row_ptr, const int* __restrict__ bofs, int N) {
  int b = blockIdx.x;
  if (b == 0) return;
  int add = bofs[b];
  int i0 = b * 1024 + threadIdx.x * 4;
#pragma unroll
  for (int m = 0; m < 4; ++m)
    if (i0 + m < N) row_ptr[i0 + m] += add;
}

// edges[p] = {src, dinv[src] bits}
__global__ void fill_kernel(const int* __restrict__ src, const int* __restrict__ dst,
                            const int* __restrict__ row_ptr, int* __restrict__ cnt2,
                            const float* __restrict__ dinv,
                            int2* __restrict__ edges, int E) {
  int e = blockIdx.x * 256 + threadIdx.x;
  if (e >= E) return;
  int s = src[e], d = dst[e];
  int p = row_ptr[d] + atomicAdd(&cnt2[d], 1);
  edges[p] = make_int2(s, __float_as_int(dinv[s]));
}

// fill padded tail records with zero-weight self edges
__global__ void pad_kernel(const int* __restrict__ cnt, const int* __restrict__ row_ptr,
                           int2* __restrict__ edges, int N) {
  int n = blockIdx.x * 256 + threadIdx.x;
  if (n >= N) return;
  int a = row_ptr[n] + cnt[n];
  int b = row_ptr[n + 1];
  for (int p = a; p < b; ++p) edges[p] = make_int2(n, 0);
}

// ---------------- weight convert: fragment-major layouts ----------------
// W1F: for (ct,tn,kb) block (512 halves), lane-major: lane=(q<<4)|l15 holds
// W1T[ct*64+tn*16+l15][kb*32+q*8+j], j=0..7. One B-fragment = 1 KB contiguous.

__global__ void convert_w1(const float* __restrict__ W1, unsigned short* __restrict__ W1F) {
  int i = blockIdx.x * 256 + threadIdx.x;
  if (i >= D_HID * D_IN) return;
  int c = i >> 8, k = i & 255;
  int ct = c >> 6, tn = (c >> 4) & 3, l15 = c & 15;
  int kb = k >> 5, q = (k >> 3) & 3, j = k & 7;
  int lane = (q << 4) | l15;
  int dst = (((ct * 4 + tn) * 8 + kb) << 9) + lane * 8 + j;
  W1F[dst] = f2bf(W1[k * D_HID + c]);
}

// W2F: block (ct,kk,tn): lane holds W2T[tn*16+l15][ct*64+kk*32+q*8+j]
__global__ void convert_w2(const float* __restrict__ W2, unsigned short* __restrict__ W2F) {
  int i = blockIdx.x * 256 + threadIdx.x;
  if (i >= D_OUT * D_HID) return;
  int n = i >> 9, k = i & 511;
  int ct = k >> 6, kk = (k >> 5) & 1, q = (k >> 3) & 3, j = k & 7;
  int tn = n >> 4, l15 = n & 15;
  int lane = (q << 4) | l15;
  int dst = (((ct * 2 + kk) * 3 + tn) << 9) + lane * 8 + j;
  W2F[dst] = f2bf(W2[k * D_OUT + n]);
}

// ---------------- fused MLP encoder: zero barriers, B-frags direct from L2 ----------------
// Wave strip M=32 (mt=2 x 16 rows). A-frags f32->bf16 in regs. Each MFMA
// B-operand is one coalesced 1 KB load from fragment-major W1F/W2F (L2-hot).
// sHid = wave-private transpose buffer (lgkmcnt only, no __syncthreads).

__global__ __launch_bounds__(256, 2) void encoder_kernel(
    const float* __restrict__ x, const float* __restrict__ b1,
    const float* __restrict__ b2,
    const unsigned short* __restrict__ W1F,   // 512x256 fragment-major
    const unsigned short* __restrict__ W2F,   // 48x512 fragment-major
    __half* __restrict__ h2, int N) {
  __shared__ unsigned short sHid[4][2][16][72];  // [wave][mt][row][col] 18.4 KB

  int tid = threadIdx.x;
  int w = tid >> 6, lane = tid & 63;
  int q = lane >> 4, l15 = lane & 15;
  int row0 = blockIdx.x * 128 + w * 32;

  // A fragments: 2 tiles x 16 rows x K=256, f32 loaded + converted (64 VGPRs)
  uint4 axu[2][8];
#pragma unroll
  for (int mt = 0; mt < 2; ++mt) {
    int grow = row0 + mt * 16 + l15;
    bool rok = grow < N;
    const float* xr = x + (size_t)grow * D_IN;
#pragma unroll
    for (int jb = 0; jb < 8; ++jb) {
      float4 v0 = make_float4(0.f, 0.f, 0.f, 0.f), v1 = v0;
      if (rok) {
        v0 = *(const float4*)(xr + jb * 32 + q * 8);
        v1 = *(const float4*)(xr + jb * 32 + q * 8 + 4);
      }
      union { uint4 u; unsigned short s[8]; } uu;
      uu.s[0] = f2bf(v0.x); uu.s[1] = f2bf(v0.y); uu.s[2] = f2bf(v0.z); uu.s[3] = f2bf(v0.w);
      uu.s[4] = f2bf(v1.x); uu.s[5] = f2bf(v1.y); uu.s[6] = f2bf(v1.z); uu.s[7] = f2bf(v1.w);
      axu[mt][jb] = uu.u;
    }
  }

  f32x4 hacc[2][3];
#pragma unroll
  for (int mt = 0; mt < 2; ++mt)
#pragma unroll
    for (int t = 0; t < 3; ++t)
#pragma unroll
      for (int r = 0; r < 4; ++r) hacc[mt][t][r] = 0.f;

  for (int ct = 0; ct < 8; ++ct) {
    int c0 = ct * 64;
    f32x4 acc[2][4];
#pragma unroll
    for (int mt = 0; mt < 2; ++mt)
#pragma unroll
      for (int t = 0; t < 4; ++t)
#pragma unroll
        for (int r = 0; r < 4; ++r) acc[mt][t][r] = 0.f;

    const unsigned short* wbase = W1F + ((size_t)(ct * 4) << 12) + lane * 8;
#pragma unroll
    for (int kb = 0; kb < 8; ++kb) {
      uint4 bq0 = *(const uint4*)(wbase + (kb << 9));
      uint4 bq1 = *(const uint4*)(wbase + (kb << 9) + 4096);
      uint4 bq2 = *(const uint4*)(wbase + (kb << 9) + 8192);
      uint4 bq3 = *(const uint4*)(wbase + (kb << 9) + 12288);
      bf16x8 a0 = __builtin_bit_cast(bf16x8, axu[0][kb]);
      bf16x8 a1 = __builtin_bit_cast(bf16x8, axu[1][kb]);
      acc[0][0] = __builtin_amdgcn_mfma_f32_16x16x32_bf16(a0, __builtin_bit_cast(bf16x8, bq0), acc[0][0], 0, 0, 0);
      acc[1][0] = __builtin_amdgcn_mfma_f32_16x16x32_bf16(a1, __builtin_bit_cast(bf16x8, bq0), acc[1][0], 0, 0, 0);
      acc[0][1] = __builtin_amdgcn_mfma_f32_16x16x32_bf16(a0, __builtin_bit_cast(bf16x8, bq1), acc[0][1], 0, 0, 0);
      acc[1][1] = __builtin_amdgcn_mfma_f32_16x16x32_bf16(a1, __builtin_bit_cast(bf16x8, bq1), acc[1][1], 0, 0, 0);
      acc[0][2] = __builtin_amdgcn_mfma_f32_16x16x32_bf16(a0, __builtin_bit_cast(bf16x8, bq2), acc[0][2], 0, 0, 0);
      acc[1][2] = __builtin_amdgcn_mfma_f32_16x16x32_bf16(a1, __builtin_bit_cast(bf16x8, bq2), acc[1][2], 0, 0, 0);
      acc[0][3] = __builtin_amdgcn_mfma_f32_16x16x32_bf16(a0, __builtin_bit_cast(bf16x8, bq3), acc[0][3], 0, 0, 0);
      acc[1][3] = __builtin_amdgcn_mfma_f32_16x16x32_bf16(a1, __builtin_bit_cast(bf16x8, bq3), acc[1][3], 0, 0, 0);
    }
    // relu(acc + b1) -> wave-private sHid (C-layout: col=l15, row=q*4+rg)
#pragma unroll
    for (int mt = 0; mt < 2; ++mt)
#pragma unroll
      for (int tn = 0; tn < 4; ++tn) {
        int c = tn * 16 + l15;
        float bias = b1[c0 + c];
#pragma unroll
        for (int rg = 0; rg < 4; ++rg) {
          float v = acc[mt][tn][rg] + bias;
          v = v > 0.f ? v : 0.f;
          sHid[w][mt][q * 4 + rg][c] = f2bf(v);
        }
      }
    // GEMM2 on this 64-col hid chunk (A from LDS, B direct from W2F)
#pragma unroll
    for (int kk = 0; kk < 2; ++kk) {
      bf16x8 a0 = *(const bf16x8*)&sHid[w][0][l15][kk * 32 + q * 8];
      bf16x8 a1 = *(const bf16x8*)&sHid[w][1][l15][kk * 32 + q * 8];
      const unsigned short* w2b = W2F + (((ct * 2 + kk) * 3) << 9) + lane * 8;
#pragma unroll
      for (int tn = 0; tn < 3; ++tn) {
        bf16x8 b = *(const bf16x8*)(w2b + (tn << 9));
        hacc[0][tn] = __builtin_amdgcn_mfma_f32_16x16x32_bf16(a0, b, hacc[0][tn], 0, 0, 0);
        hacc[1][tn] = __builtin_amdgcn_mfma_f32_16x16x32_bf16(a1, b, hacc[1][tn], 0, 0, 0);
      }
    }
  }
  // epilogue: h2 = f16(hacc + b2), HPAD stride, pad cols 48..63 zeroed
#pragma unroll
  for (int mt = 0; mt < 2; ++mt) {
#pragma unroll
    for (int tn = 0; tn < 3; ++tn) {
      int c = tn * 16 + l15;
      float bias = b2[c];
#pragma unroll
      for (int rg = 0; rg < 4; ++rg) {
        int gr = row0 + mt * 16 + q * 4 + rg;
        if (gr < N) h2[(size_t)gr * HPAD + c] = __float2half(hacc[mt][tn][rg] + bias);
      }
    }
#pragma unroll
    for (int rg = 0; rg < 4; ++rg) {
      int gr = row0 + mt * 16 + q * 4 + rg;
      if (gr < N) h2[(size_t)gr * HPAD + 48 + l15] = __float2half(0.f);
    }
  }
}

// ---------------- APPNP propagation: 2 nodes/wave, 4 slots x 8 lanes ----------------
// 128-B padded rows (round-4 measured-best) + unroll-2: 2 gathers in flight.

__global__ __launch_bounds__(256) void prop_kernel(
    const __half* __restrict__ cur, const __half* __restrict__ h2,
    const float* __restrict__ dinv, const int* __restrict__ row_ptr,
    const int2* __restrict__ edges, __half* __restrict__ nxt,
    float* __restrict__ outf, int N, int last) {
  int wid = (blockIdx.x * 256 + threadIdx.x) >> 6;
  int lane = threadIdx.x & 63;
  int half = lane >> 5;
  int slot = (lane >> 3) & 3;
  int s = lane & 7;
  int node = wid * 2 + half;
  bool nok = node < N;
  int p0 = 0, p1 = 0;
  if (nok) { int2 pp = *(const int2*)(row_ptr + node); p0 = pp.x; p1 = pp.y; }
  int d = p1 - p0;                          // padded degree (mult of 4)
  int dmax = max(d, __shfl_xor(d, 32));     // pair max (wave-uniform)
  int nb = dmax >> 2;

  float acc[8];
#pragma unroll
  for (int i = 0; i < 8; ++i) acc[i] = 0.f;

  int p = p0 + slot;
  int2 e0 = make_int2(0, 0), e1 = make_int2(0, 0);
  if (nb > 0) e0 = edges[p];
  if (nb > 1) e1 = edges[p + 4];
  int b = 0;
  for (; b + 2 <= nb; b += 2) {
    int2 n0 = make_int2(0, 0), n1 = make_int2(0, 0);
    if (b + 2 < nb) n0 = edges[p + 8];      // prefetch (uniform branches)
    if (b + 3 < nb) n1 = edges[p + 12];
    float w0 = (p < p1) ? __int_as_float(e0.y) : 0.f;
    float w1 = (p + 4 < p1) ? __int_as_float(e1.y) : 0.f;
    union { float4 f; __half2 h[4]; } u0, u1;
    u0.f = *(const float4*)(cur + ((size_t)e0.x << 6) + s * 8);
    u1.f = *(const float4*)(cur + ((size_t)e1.x << 6) + s * 8);
#pragma unroll
    for (int i = 0; i < 4; ++i) {
      float2 f0 = __half22float2(u0.h[i]);
      float2 f1 = __half22float2(u1.h[i]);
      acc[2 * i]     += w0 * f0.x + w1 * f1.x;
      acc[2 * i + 1] += w0 * f0.y + w1 * f1.y;
    }
    e0 = n0; e1 = n1; p += 8;
  }
  if (b < nb) {
    float w0 = (p < p1) ? __int_as_float(e0.y) : 0.f;
    union { float4 f; __half2 h[4]; } u0;
    u0.f = *(const float4*)(cur + ((size_t)e0.x << 6) + s * 8);
#pragma unroll
    for (int i = 0; i < 4; ++i) {
      float2 f0 = __half22float2(u0.h[i]);
      acc[2 * i]     += w0 * f0.x;
      acc[2 * i + 1] += w0 * f0.y;
    }
  }
  // fold the 4 slots (lane bits 3,4) via fixed-pattern swizzles
#pragma unroll
  for (int i = 0; i < 8; ++i) {
    acc[i] += __int_as_float(__builtin_amdgcn_ds_swizzle(__float_as_int(acc[i]), 0x201F)); // ^8
    acc[i] += __int_as_float(__builtin_amdgcn_ds_swizzle(__float_as_int(acc[i]), 0x401F)); // ^16
  }
  if ((lane & 24) != 0 || !nok) return;
  float di = dinv[node];
  size_t base = ((size_t)node << 6) + s * 8;
  union { float4 f; __half2 h[4]; } us, uh;
  us.f = *(const float4*)(cur + base);
  uh.f = *(const float4*)(h2 + base);
  float dii = di * di;
  float outv[8];
#pragma unroll
  for (int i = 0; i < 4; ++i) {
    float2 sf = __half22float2(us.h[i]);
    float2 hf = __half22float2(uh.h[i]);
    outv[2 * i]     = 0.9f * (di * acc[2 * i]     + dii * sf.x) + 0.1f * hf.x;
    outv[2 * i + 1] = 0.9f * (di * acc[2 * i + 1] + dii * sf.y) + 0.1f * hf.y;
  }
  if (last) {
    if (s < 6) {  // only the 48 real features
      float* op = outf + (size_t)node * D_OUT + s * 8;
      *(float4*)op       = make_float4(outv[0], outv[1], outv[2], outv[3]);
      *(float4*)(op + 4) = make_float4(outv[4], outv[5], outv[6], outv[7]);
    }
  } else {
    union { uint4 u4; __half2 h[4]; } o;
#pragma unroll
    for (int i = 0; i < 4; ++i) o.h[i] = __floats2half2_rn(outv[2 * i], outv[2 * i + 1]);
    *(uint4*)(nxt + base) = o.u4;
  }
}

// ---------------- launch ----------------

extern "C" void kernel_launch(void* const* d_in, const int* in_sizes, int n_in,
                              void* d_out, int out_size, void* d_ws, size_t ws_size,
                              hipStream_t stream) {
  (void)n_in; (void)out_size; (void)ws_size;
  const float* x  = (const float*)d_in[0];
  const int*   ei = (const int*)d_in[1];
  const float* W1 = (const float*)d_in[2];
  const float* b1 = (const float*)d_in[3];
  const float* W2 = (const float*)d_in[4];
  const float* b2 = (const float*)d_in[5];
  const int N = in_sizes[0] / D_IN;
  const int E = in_sizes[1] / 2;
  const int* e_src = ei;
  const int* e_dst = ei + E;

  char* ws = (char*)d_ws;
  size_t off = 0;
  auto take = [&](size_t bytes) -> char* {
    char* p = ws + off;
    off += (bytes + 511) & ~(size_t)511;
    return p;
  };
  int* cnt      = (int*)take((size_t)N * 4);
  int* cnt2     = (int*)take((size_t)N * 4);
  float* dinv   = (float*)take((size_t)N * 4);
  int* row_ptr  = (int*)take((size_t)(N + 1) * 4);
  int* bsum     = (int*)take(1024);
  int* bofs     = (int*)take(1024);
  int2* edges   = (int2*)take(((size_t)E + 4 * (size_t)N) * 8);  // padded CSR
  unsigned short* W1F = (unsigned short*)take((size_t)D_IN * D_HID * 2);
  unsigned short* W2F = (unsigned short*)take((size_t)D_HID * D_OUT * 2);
  __half* h2    = (__half*)take((size_t)N * HPAD * 2);
  __half* bufA  = (__half*)take((size_t)N * HPAD * 2);
  __half* bufB  = (__half*)d_out;   // 19.2 MB f32 out region holds 12.8 MB f16 buf;
                                    // last read of bufB precedes final f32 write
  float* outp   = (float*)d_out;

  int nb256 = (N + 255) / 256;
  int eb256 = (E + 255) / 256;
  int NB    = (N + 1023) / 1024;   // 98 <= 128 ok

  // graph build (padded CSR)
  zero2_kernel<<<nb256, 256, 0, stream>>>(cnt, cnt2, N);
  count_kernel<<<eb256, 256, 0, stream>>>(e_dst, cnt, E);
  dinv_kernel<<<nb256, 256, 0, stream>>>(cnt, dinv, N);
  scan1_kernel<<<NB, 256, 0, stream>>>(cnt, row_ptr, bsum, N);
  scan2_kernel<<<1, 128, 0, stream>>>(bsum, bofs, row_ptr, NB, N);
  scan3_kernel<<<NB, 256, 0, stream>>>(row_ptr, bofs, N);
  fill_kernel<<<eb256, 256, 0, stream>>>(e_src, e_dst, row_ptr, cnt2, dinv, edges, E);
  pad_kernel<<<nb256, 256, 0, stream>>>(cnt, row_ptr, edges, N);

  // weight permute + encoder
  convert_w1<<<(D_IN * D_HID + 255) / 256, 256, 0, stream>>>(W1, W1F);
  convert_w2<<<(D_HID * D_OUT + 255) / 256, 256, 0, stream>>>(W2, W2F);
  encoder_kernel<<<(N + 127) / 128, 256, 0, stream>>>(x, b1, b2, W1F, W2F, h2, N);

  // APPNP: 10 iters; h2 -> A -> B(d_out) -> A ... ; last writes f32 d_out
  int waves = (N + 1) / 2;
  int pblocks = (waves + 3) / 4;
  const __half* src = h2;
  __half* dst = bufA;
  for (int it = 1; it <= K_STEPS; ++it) {
    int last = (it == K_STEPS);
    prop_kernel<<<pblocks, 256, 0, stream>>>(src, h2, dinv, row_ptr, edges,
                                             dst, outp, N, last);
    src = dst;
    dst = (dst == bufA) ? bufB : bufA;
  }
}